// Round 5
// baseline (362.135 us; speedup 1.0000x reference)
//
#include <hip/hip_runtime.h>
#include <hip/hip_cooperative_groups.h>

// B=64, N=2048, DIM_IN=DIM_OUT=64, CHEB_K=3, EMBED_DIM=10
#define NN 2048
#define BB 64
#define CC 64
#define ED 10
#define KK 3
#define JJ (BB * CC)   // 4096

typedef unsigned short ushort_t;
typedef __attribute__((ext_vector_type(8))) short short8;   // 8 bf16 = 4 VGPRs
typedef __attribute__((ext_vector_type(4))) float f32x4;

typedef const __attribute__((address_space(1))) unsigned* gptr_t;
typedef __attribute__((address_space(3))) unsigned* lptr_t;

static __device__ __forceinline__ ushort_t f2bf(float f) {
    union { float f; unsigned u; } x{f};
    unsigned r = x.u + 0x7FFF + ((x.u >> 16) & 1);  // RTN-even
    return (ushort_t)(r >> 16);
}
static __device__ __forceinline__ float bf2f(ushort_t h) {
    union { unsigned u; float f; } x;
    x.u = ((unsigned)h) << 16;
    return x.f;
}

// ---------------------------------------------------------------------------
// Kernel 1 (merged prep): blockIdx selects role.
//   [0, NN)            : supports — A_bf16[n][m] = softmax(relu(E E^T)) row n
//   [NN, 2*NN)         : transpose — x[b][n][c] -> xT[(b*64+c)][n], xN[n][j]
//   [2*NN, 2*NN+30)    : wprep — Wp[d][k][i][o] fp32 -> WpT[(d*3+k)][o][i] bf16
// ---------------------------------------------------------------------------
__global__ __launch_bounds__(256) void prep_kernel(const float* __restrict__ E,
                                                   const float* __restrict__ x,
                                                   const float* __restrict__ Wp,
                                                   ushort_t* __restrict__ Ab,
                                                   ushort_t* __restrict__ xT,
                                                   ushort_t* __restrict__ xN,
                                                   ushort_t* __restrict__ WpT) {
    const int bid = blockIdx.x;
    const int tid = threadIdx.x;

    __shared__ float tb[64][68];
    __shared__ float red[8];

    if (bid < NN) {
        // ---- supports row n = bid ----
        const int n = bid;
        float en[ED];
#pragma unroll
        for (int d = 0; d < ED; ++d) en[d] = E[n * ED + d];

        float sv[NN / 256];
        float lmax = 0.0f;  // relu >= 0
#pragma unroll
        for (int j = 0; j < NN / 256; ++j) {
            const int m = tid + j * 256;
            const float* Em = E + m * ED;
            float dot = 0.0f;
#pragma unroll
            for (int d = 0; d < ED; ++d) dot += en[d] * Em[d];
            float s = fmaxf(dot, 0.0f);
            sv[j] = s;
            lmax = fmaxf(lmax, s);
        }
#pragma unroll
        for (int off = 32; off > 0; off >>= 1) lmax = fmaxf(lmax, __shfl_down(lmax, off, 64));
        if ((tid & 63) == 0) red[tid >> 6] = lmax;
        __syncthreads();
        const float bmax = fmaxf(fmaxf(red[0], red[1]), fmaxf(red[2], red[3]));

        float lsum = 0.0f;
#pragma unroll
        for (int j = 0; j < NN / 256; ++j) {
            sv[j] = __expf(sv[j] - bmax);
            lsum += sv[j];
        }
#pragma unroll
        for (int off = 32; off > 0; off >>= 1) lsum += __shfl_down(lsum, off, 64);
        if ((tid & 63) == 0) red[4 + (tid >> 6)] = lsum;
        __syncthreads();
        const float inv = 1.0f / (red[4] + red[5] + red[6] + red[7]);

#pragma unroll
        for (int j = 0; j < NN / 256; ++j) {
            Ab[(size_t)n * NN + tid + j * 256] = f2bf(sv[j] * inv);
        }
    } else if (bid < 2 * NN) {
        // ---- transpose tile ----
        const int t = bid - NN;
        const int n0 = (t & 31) * 64;
        const int b = t >> 5;

#pragma unroll
        for (int l = 0; l < 4; ++l) {
            const int idx = tid + l * 256;
            const int nn = idx >> 4;
            const int c4 = (idx & 15) << 2;
            const float4 v = *(const float4*)(x + ((size_t)b * NN + n0 + nn) * CC + c4);
            tb[c4 + 0][nn] = v.x;
            tb[c4 + 1][nn] = v.y;
            tb[c4 + 2][nn] = v.z;
            tb[c4 + 3][nn] = v.w;
        }
        __syncthreads();

#pragma unroll
        for (int l = 0; l < 2; ++l) {
            const int idx = tid + l * 256;
            const int c = idx >> 3;
            const int ch = (idx & 7) << 3;
            ushort_t pack[8];
#pragma unroll
            for (int e = 0; e < 8; ++e) pack[e] = f2bf(tb[c][ch + e]);
            *(float4*)(xT + (size_t)(b * 64 + c) * NN + n0 + ch) = *(float4*)pack;
        }
#pragma unroll
        for (int l = 0; l < 2; ++l) {
            const int idx = tid + l * 256;
            const int nn = idx >> 3;
            const int cg = (idx & 7) << 3;
            ushort_t pack[8];
#pragma unroll
            for (int e = 0; e < 8; ++e) pack[e] = f2bf(tb[cg + e][nn]);
            *(float4*)(xN + (size_t)(n0 + nn) * JJ + b * 64 + cg) = *(float4*)pack;
        }
    } else {
        // ---- wprep slice dk = bid - 2*NN ----
        const int dk = bid - 2 * NN;
        const float* src = Wp + (size_t)dk * CC * CC;

#pragma unroll
        for (int l = 0; l < 4; ++l) {
            const int idx = tid + l * 256;
            const int i = idx >> 4;
            const int o4 = (idx & 15) << 2;
            const float4 v = *(const float4*)(src + i * CC + o4);
            tb[o4 + 0][i] = v.x;
            tb[o4 + 1][i] = v.y;
            tb[o4 + 2][i] = v.z;
            tb[o4 + 3][i] = v.w;
        }
        __syncthreads();

#pragma unroll
        for (int l = 0; l < 2; ++l) {
            const int idx = tid + l * 256;
            const int o = idx >> 3;
            const int ic = (idx & 7) << 3;
            ushort_t pack[8];
#pragma unroll
            for (int e = 0; e < 8; ++e) pack[e] = f2bf(tb[o][ic + e]);
            *(float4*)(WpT + (size_t)dk * CC * CC + o * CC + ic) = *(float4*)pack;
        }
    }
}

// ---------------------------------------------------------------------------
// Kernel 2: cooperative fused GEMM chain.
//   Phase A: y1 = A @ x            (dual write: y1T K-major + y1N node-major)
//   grid.sync()
//   Phase B: y2 = 2*A @ y1 - x     (node-major)
// Tiles 128x256 (BM x BN), BK=64: 16 m-tiles x 16 j-tiles = 256 blocks =
// 1 block/CU (96 KB LDS). 8 waves = 2M x 4N, per-wave 64x64 output.
// K-loop = round-4's verified ROLLED schedule re-derived for this shape:
//   stage units: A = 2 x 8KB, B = 4 x 8KB per tile (6 loads/tile).
//   R1: t_b B-lo | R2: t_b B-hi | R3: t_a+2 B-lo | R4: t_a+2 B-hi, vmcnt(4)
//   R5: t_a+2 A  | R8: t_b+2 A, vmcnt(2).   Prologue: t0 full + t1 A, vmcnt(2).
// Every stage lands >=2 regions after the last fenced read of its LDS region
// (B reads of a buf complete at its 2nd region, A reads at its 3rd).
// ---------------------------------------------------------------------------
#define STAGE_A(buf, kt) do {                                                               \
    __builtin_amdgcn_global_load_lds(                                                       \
        (gptr_t)(srcA + (size_t)(kt) * 64),                                                 \
        (lptr_t)&lds[buf][dstoff], 16, 0, 0);                                               \
    __builtin_amdgcn_global_load_lds(                                                       \
        (gptr_t)(srcA + (size_t)64 * NN + (size_t)(kt) * 64),                               \
        (lptr_t)&lds[buf][4096 + dstoff], 16, 0, 0);                                        \
} while (0)

#define STAGE_B(buf, half, kt) do {                                                         \
    __builtin_amdgcn_global_load_lds(                                                       \
        (gptr_t)(srcB + (size_t)((half) * 2) * 64 * NN + (size_t)(kt) * 64),                \
        (lptr_t)&lds[buf][8192 + ((half) * 2) * 4096 + dstoff], 16, 0, 0);                  \
    __builtin_amdgcn_global_load_lds(                                                       \
        (gptr_t)(srcB + (size_t)((half) * 2 + 1) * 64 * NN + (size_t)(kt) * 64),            \
        (lptr_t)&lds[buf][8192 + ((half) * 2 + 1) * 4096 + dstoff], 16, 0, 0);              \
} while (0)

#define LDA_Q(buf, qm) do {                                                                 \
    _Pragma("unroll") for (int mi_ = 0; mi_ < 2; ++mi_)                                     \
    _Pragma("unroll") for (int ks_ = 0; ks_ < 2; ++ks_)                                     \
        a[mi_][ks_] = *(const short8*)&lds[buf][((aRG + (qm) * 2 + mi_) * 2 + ks_) * 512 + rdofs]; \
} while (0)

#define LDB_Q(buf, qn) do {                                                                 \
    _Pragma("unroll") for (int ni_ = 0; ni_ < 2; ++ni_)                                     \
    _Pragma("unroll") for (int ks_ = 0; ks_ < 2; ++ks_)                                     \
        b[(qn) * 2 + ni_][ks_] = *(const short8*)&lds[buf][8192 + ((bRG + (qn) * 2 + ni_) * 2 + ks_) * 512 + rdofs]; \
} while (0)

#define MFMA_Q(qm, qn) do {                                                                 \
    __builtin_amdgcn_s_setprio(1);                                                          \
    _Pragma("unroll") for (int mi_ = 0; mi_ < 2; ++mi_)                                     \
    _Pragma("unroll") for (int nn_ = 0; nn_ < 2; ++nn_) {                                   \
        acc[(qm) * 2 + mi_][(qn) * 2 + nn_] = __builtin_amdgcn_mfma_f32_16x16x32_bf16(      \
            a[mi_][0], b[(qn) * 2 + nn_][0], acc[(qm) * 2 + mi_][(qn) * 2 + nn_], 0, 0, 0); \
        acc[(qm) * 2 + mi_][(qn) * 2 + nn_] = __builtin_amdgcn_mfma_f32_16x16x32_bf16(      \
            a[mi_][1], b[(qn) * 2 + nn_][1], acc[(qm) * 2 + mi_][(qn) * 2 + nn_], 0, 0, 0); \
    }                                                                                       \
    __builtin_amdgcn_s_setprio(0);                                                          \
} while (0)

#define WAIT_READS do {                                                                     \
    __builtin_amdgcn_s_barrier();                                                           \
    asm volatile("s_waitcnt lgkmcnt(0)" ::: "memory");                                      \
    __builtin_amdgcn_sched_barrier(0);                                                      \
} while (0)

#define REGION_END do {                                                                     \
    __builtin_amdgcn_sched_barrier(0);                                                      \
    __builtin_amdgcn_s_barrier();                                                           \
} while (0)

// K = 2048 = 32 tiles of BK=64; 16 iterations x 2 tiles (buf0 even, buf1 odd).
#define KLOOP() do {                                                                        \
    _Pragma("unroll") for (int mi = 0; mi < 4; ++mi)                                        \
    _Pragma("unroll") for (int ni = 0; ni < 4; ++ni)                                        \
        acc[mi][ni] = (f32x4){0.f, 0.f, 0.f, 0.f};                                          \
    STAGE_B(0, 0, 0); STAGE_B(0, 1, 0); STAGE_A(0, 0);                                      \
    STAGE_A(1, 1);                                                                          \
    asm volatile("s_waitcnt vmcnt(2)" ::: "memory");                                        \
    __builtin_amdgcn_s_barrier();                                                           \
    _Pragma("unroll 1") for (int i = 0; i < 16; ++i) {                                      \
        const int tb_ = 2 * i + 1, ta2 = 2 * i + 2, tb2 = 2 * i + 3;                        \
        const bool stg = (i < 15);                                                          \
        /* R1 */                                                                            \
        if (i) MFMA_Q(1, 0);                                                                \
        LDA_Q(0, 0); LDB_Q(0, 0);                                                           \
        STAGE_B(1, 0, tb_);                                                                 \
        WAIT_READS; MFMA_Q(0, 0); LDB_Q(0, 1); REGION_END;                                  \
        /* R2 */                                                                            \
        STAGE_B(1, 1, tb_);                                                                 \
        WAIT_READS; MFMA_Q(0, 1); LDA_Q(0, 1); REGION_END;                                  \
        /* R3 */                                                                            \
        if (stg) STAGE_B(0, 0, ta2);                                                        \
        WAIT_READS; MFMA_Q(1, 1); REGION_END;                                               \
        /* R4: drain t_b */                                                                 \
        if (stg) { STAGE_B(0, 1, ta2);                                                      \
                   asm volatile("s_waitcnt vmcnt(4)" ::: "memory"); }                       \
        else     { asm volatile("s_waitcnt vmcnt(0)" ::: "memory"); }                       \
        __builtin_amdgcn_s_barrier();                                                       \
        /* R5: deferred quadrant covers buf1 top reads */                                   \
        MFMA_Q(1, 0);                                                                       \
        LDA_Q(1, 0); LDB_Q(1, 0);                                                           \
        if (stg) STAGE_A(0, ta2);                                                           \
        WAIT_READS; MFMA_Q(0, 0); LDB_Q(1, 1); REGION_END;                                  \
        /* R6 */                                                                            \
        asm volatile("s_waitcnt lgkmcnt(0)" ::: "memory");                                  \
        __builtin_amdgcn_sched_barrier(0);                                                  \
        MFMA_Q(0, 1); LDA_Q(1, 1); REGION_END;                                              \
        /* R7 */                                                                            \
        asm volatile("s_waitcnt lgkmcnt(0)" ::: "memory");                                  \
        __builtin_amdgcn_sched_barrier(0);                                                  \
        MFMA_Q(1, 1); REGION_END;                                                           \
        /* R8: drain t_a+2 */                                                               \
        if (stg) { STAGE_A(1, tb2);                                                         \
                   asm volatile("s_waitcnt vmcnt(2)" ::: "memory"); }                       \
        __builtin_amdgcn_s_barrier();                                                       \
    }                                                                                       \
    MFMA_Q(1, 0);                                                                           \
} while (0)

__global__ __launch_bounds__(512, 2) void gemm_fused(const ushort_t* __restrict__ Ab,
                                                     const ushort_t* __restrict__ xT,
                                                     ushort_t* __restrict__ y1T,
                                                     const ushort_t* __restrict__ xN,
                                                     ushort_t* __restrict__ y1N,
                                                     ushort_t* __restrict__ y2N) {
    // bijective XCD swizzle (gridDim.x = 256, 256 % 8 == 0)
    int bid = blockIdx.x;
    bid = (bid & 7) * 32 + (bid >> 3);
    const int bx = bid & 15;        // j-tile (BN=256)
    const int by = bid >> 4;        // m-tile (BM=128)
    const int j0 = bx * 256;
    const int m0 = by * 128;

    const int tid = threadIdx.x;
    const int w = tid >> 6;
    const int lane = tid & 63;
    const int l16 = lane & 15;
    const int quad = lane >> 4;
    const int wm = (w >> 2) * 64;   // wave rows [wm, wm+64)
    const int wn = (w & 3) * 64;    // wave cols [wn, wn+64)
    const int aRG = (w >> 2) * 4;   // A subtile group base (8 subtiles total)
    const int bRG = (w & 3) * 4;    // B subtile group base (16 subtiles total)
    // swizzled ds_read offset (ushorts): row l16, k-chunk quad, st_16x32 XOR
    const int rdofs = l16 * 32 + ((quad * 8) ^ ((l16 & 8) * 2));

    // staging: linear LDS dest (tid*16B within 8KB unit); inverse-swz SOURCE
    const int r16s = lane >> 2;
    const int cx = (lane & 3) ^ ((r16s >> 3) << 1);
    const int rowbase = (w >> 1) * 16 + r16s;         // row within 64-row unit
    const int kofs = (w & 1) * 32 + cx * 8;
    const ushort_t* srcA = Ab + (size_t)m0 * NN + (size_t)rowbase * NN + kofs;
    const ushort_t* srcB;  // set per phase
    const int dstoff = tid * 8;

    __shared__ ushort_t lds[2][24576];  // [dbuf][A 16KB | B 32KB] = 96 KB

    f32x4 acc[4][4];
    short8 a[2][2], b[4][2];

    // ---------------- Phase A: y1 = A @ x ----------------
    srcB = xT + (size_t)j0 * NN + (size_t)rowbase * NN + kofs;
    KLOOP();

    // epilogue A: dual write. C/D: col j = l16, row m = quad*4 + r.
#pragma unroll
    for (int mi = 0; mi < 4; ++mi) {
#pragma unroll
        for (int ji = 0; ji < 4; ++ji) {
            const int j = j0 + wn + ji * 16 + l16;
            const int mb = m0 + wm + mi * 16 + quad * 4;
            ushort_t o[4];
#pragma unroll
            for (int r = 0; r < 4; ++r) o[r] = f2bf(acc[mi][ji][r]);
            *(unsigned long long*)(y1T + (size_t)j * NN + mb) = *(unsigned long long*)o;
#pragma unroll
            for (int r = 0; r < 4; ++r) y1N[(size_t)(mb + r) * JJ + j] = o[r];
        }
    }

    __threadfence();                       // release y1T device-wide
    cooperative_groups::this_grid().sync();
    __threadfence();                       // acquire (invalidate stale L2)

    // ---------------- Phase B: y2 = 2*A @ y1 - x ----------------
    srcB = y1T + (size_t)j0 * NN + (size_t)rowbase * NN + kofs;
    KLOOP();

#pragma unroll
    for (int mi = 0; mi < 4; ++mi) {
#pragma unroll
        for (int ji = 0; ji < 4; ++ji) {
            const int j = j0 + wn + ji * 16 + l16;
            const int mb = m0 + wm + mi * 16 + quad * 4;
#pragma unroll
            for (int r = 0; r < 4; ++r) {
                const float z = bf2f(xN[(size_t)(mb + r) * JJ + j]);
                y2N[(size_t)(mb + r) * JJ + j] = f2bf(2.0f * acc[mi][ji][r] - z);
            }
        }
    }
}

#undef STAGE_A
#undef STAGE_B
#undef LDA_Q
#undef LDB_Q
#undef MFMA_Q
#undef WAIT_READS
#undef REGION_END
#undef KLOOP

// ---------------------------------------------------------------------------
// Kernel 3: MFMA epilogue (unchanged, verified).
// One block per node n: [B=64 x KI=192] @ [KI=192 x O=64] via 24 MFMAs/wave.
// ---------------------------------------------------------------------------
#define XLD 200  // LDS row stride (bf16): 400 B -> 2-way bank alias (free)
__global__ __launch_bounds__(256) void out_kernel(const float* __restrict__ E,
                                                  const ushort_t* __restrict__ WpT,
                                                  const float* __restrict__ bp,
                                                  const ushort_t* __restrict__ xN,
                                                  const ushort_t* __restrict__ y1N,
                                                  const ushort_t* __restrict__ y2N,
                                                  float* __restrict__ out) {
    const int n = blockIdx.x;
    const int tid = threadIdx.x;

    __shared__ ushort_t xg[BB * XLD];  // 25.6 KB: xg[b][k*64+i]
    __shared__ ushort_t Wt[CC * XLD];  // 25.6 KB: Wt[o][k*64+i]
    __shared__ float en_s[ED];
    __shared__ float bias_s[CC];

    if (tid < ED) en_s[tid] = E[n * ED + tid];
    __syncthreads();

    float en[ED];
#pragma unroll
    for (int d = 0; d < ED; ++d) en[d] = en_s[d];

    if (tid < CC) {
        float bsum = 0.0f;
#pragma unroll
        for (int d = 0; d < ED; ++d) bsum += en[d] * bp[d * CC + tid];
        bias_s[tid] = bsum;
    }

    // stage X rows: 3 sources x 512 chunks of 8 bf16 (contiguous 8 KB each)
#pragma unroll
    for (int k = 0; k < KK; ++k) {
        const ushort_t* src = (k == 0) ? xN : (k == 1) ? y1N : y2N;
        const float4* srow = (const float4*)(src + (size_t)n * JJ);
        for (int idx = tid; idx < JJ / 8; idx += 256) {
            *(float4*)&xg[(idx >> 3) * XLD + k * 64 + ((idx & 7) << 3)] = srow[idx];
        }
    }

    // synthesize Wt[o][ki] bf16: 1536 chunks of 8, fp32 accumulate over d
    for (int t = tid; t < CC * 24; t += 256) {
        const int o = t / 24;
        const int kc = t % 24;
        const int k = kc >> 3;
        const int ic = (kc & 7) << 3;
        float s[8];
#pragma unroll
        for (int e = 0; e < 8; ++e) s[e] = 0.0f;
#pragma unroll
        for (int d = 0; d < ED; ++d) {
            const float4 wv4 = *(const float4*)(WpT + ((size_t)(d * KK + k) * CC + o) * CC + ic);
            const ushort_t* wp = (const ushort_t*)&wv4;
#pragma unroll
            for (int e = 0; e < 8; ++e) s[e] += en[d] * bf2f(wp[e]);
        }
        ushort_t pack[8];
#pragma unroll
        for (int e = 0; e < 8; ++e) pack[e] = f2bf(s[e]);
        *(float4*)&Wt[o * XLD + k * 64 + ic] = *(float4*)pack;
    }
    __syncthreads();

    const int lane = tid & 63;
    const int l16 = lane & 15;
    const int quad = lane >> 4;
    const int bm = (tid >> 6) * 16;  // wave's 16 b-rows

    f32x4 acc[4];
#pragma unroll
    for (int ji = 0; ji < 4; ++ji) acc[ji] = (f32x4){0.f, 0.f, 0.f, 0.f};

#pragma unroll
    for (int kc = 0; kc < 6; ++kc) {  // K = 192 = 6 x 32
        const short8 av = *(const short8*)&xg[(bm + l16) * XLD + kc * 32 + quad * 8];
#pragma unroll
        for (int ji = 0; ji < 4; ++ji) {
            const short8 bv = *(const short8*)&Wt[(ji * 16 + l16) * XLD + kc * 32 + quad * 8];
            acc[ji] = __builtin_amdgcn_mfma_f32_16x16x32_bf16(av, bv, acc[ji], 0, 0, 0);
        }
    }

    // C/D: col o = l16 + 16*ji, row b = bm + quad*4 + r.
#pragma unroll
    for (int ji = 0; ji < 4; ++ji) {
        const int o = ji * 16 + l16;
        const float bo = bias_s[o];
#pragma unroll
        for (int r = 0; r < 4; ++r) {
            const int b = bm + quad * 4 + r;
            out[((size_t)b * NN + n) * CC + o] = acc[ji][r] + bo;
        }
    }
}
#undef XLD

// ---------------------------------------------------------------------------
// Host launch: 3 dispatches (prep -> cooperative fused GEMM chain -> out).
// Workspace (bf16): Ab 8 | xT 16 | xN 16 | y1T 16 | y1N 16 | y2N 16
//   | WpT 0.24  = 88.25 MB (same as round-0 baseline).
// ---------------------------------------------------------------------------
extern "C" void kernel_launch(void* const* d_in, const int* in_sizes, int n_in,
                              void* d_out, int out_size, void* d_ws, size_t ws_size,
                              hipStream_t stream) {
    const float* x  = (const float*)d_in[0];
    const float* E  = (const float*)d_in[1];
    const float* Wp = (const float*)d_in[2];
    const float* bp = (const float*)d_in[3];

    ushort_t* Ab  = (ushort_t*)d_ws;                    // [2048][2048]
    ushort_t* xT  = Ab + (size_t)NN * NN;               // [4096][2048]
    ushort_t* xN  = xT + (size_t)JJ * NN;               // [2048][4096]
    ushort_t* y1T = xN + (size_t)NN * JJ;               // [4096][2048]
    ushort_t* y1N = y1T + (size_t)JJ * NN;              // [2048][4096]
    ushort_t* y2N = y1N + (size_t)NN * JJ;              // [2048][4096]
    ushort_t* WpT = y2N + (size_t)NN * JJ;              // [30][64][64]
    float* out = (float*)d_out;

    prep_kernel<<<2 * NN + ED * KK, 256, 0, stream>>>(E, x, Wp, Ab, xT, xN, WpT);

    void* args[] = {(void*)&Ab, (void*)&xT, (void*)&y1T, (void*)&xN,
                    (void*)&y1N, (void*)&y2N};
    hipLaunchCooperativeKernel((const void*)gemm_fused, dim3(256), dim3(512),
                               args, 0, stream);

    out_kernel<<<NN, 256, 0, stream>>>(E, WpT, bp, xN, y1N, y2N, out);
}

// Round 6
// 204.361 us; speedup vs baseline: 1.7720x; 1.7720x over previous
//
#include <hip/hip_runtime.h>

// B=64, N=2048, DIM_IN=DIM_OUT=64, CHEB_K=3, EMBED_DIM=10
#define NN 2048
#define BB 64
#define CC 64
#define ED 10
#define KK 3
#define JJ (BB * CC)   // 4096

typedef unsigned short ushort_t;
typedef __attribute__((ext_vector_type(8))) short short8;   // 8 bf16 = 4 VGPRs
typedef __attribute__((ext_vector_type(4))) float f32x4;

typedef const __attribute__((address_space(1))) unsigned* gptr_t;
typedef __attribute__((address_space(3))) unsigned* lptr_t;
typedef __attribute__((address_space(3))) ushort_t* lsptr_t;
typedef const __attribute__((address_space(3))) short8* ls8_t;

static __device__ __forceinline__ ushort_t f2bf(float f) {
    union { float f; unsigned u; } x{f};
    unsigned r = x.u + 0x7FFF + ((x.u >> 16) & 1);  // RTN-even
    return (ushort_t)(r >> 16);
}
static __device__ __forceinline__ float bf2f(ushort_t h) {
    union { unsigned u; float f; } x;
    x.u = ((unsigned)h) << 16;
    return x.f;
}

// ---------------------------------------------------------------------------
// Kernel 1 (merged prep): identical to the verified round-0 version.
// ---------------------------------------------------------------------------
__global__ __launch_bounds__(256) void prep_kernel(const float* __restrict__ E,
                                                   const float* __restrict__ x,
                                                   const float* __restrict__ Wp,
                                                   ushort_t* __restrict__ Ab,
                                                   ushort_t* __restrict__ xT,
                                                   ushort_t* __restrict__ xN,
                                                   ushort_t* __restrict__ WpT) {
    const int bid = blockIdx.x;
    const int tid = threadIdx.x;

    __shared__ float tb[64][68];
    __shared__ float red[8];

    if (bid < NN) {
        const int n = bid;
        float en[ED];
#pragma unroll
        for (int d = 0; d < ED; ++d) en[d] = E[n * ED + d];

        float sv[NN / 256];
        float lmax = 0.0f;
#pragma unroll
        for (int j = 0; j < NN / 256; ++j) {
            const int m = tid + j * 256;
            const float* Em = E + m * ED;
            float dot = 0.0f;
#pragma unroll
            for (int d = 0; d < ED; ++d) dot += en[d] * Em[d];
            float s = fmaxf(dot, 0.0f);
            sv[j] = s;
            lmax = fmaxf(lmax, s);
        }
#pragma unroll
        for (int off = 32; off > 0; off >>= 1) lmax = fmaxf(lmax, __shfl_down(lmax, off, 64));
        if ((tid & 63) == 0) red[tid >> 6] = lmax;
        __syncthreads();
        const float bmax = fmaxf(fmaxf(red[0], red[1]), fmaxf(red[2], red[3]));

        float lsum = 0.0f;
#pragma unroll
        for (int j = 0; j < NN / 256; ++j) {
            sv[j] = __expf(sv[j] - bmax);
            lsum += sv[j];
        }
#pragma unroll
        for (int off = 32; off > 0; off >>= 1) lsum += __shfl_down(lsum, off, 64);
        if ((tid & 63) == 0) red[4 + (tid >> 6)] = lsum;
        __syncthreads();
        const float inv = 1.0f / (red[4] + red[5] + red[6] + red[7]);

#pragma unroll
        for (int j = 0; j < NN / 256; ++j) {
            Ab[(size_t)n * NN + tid + j * 256] = f2bf(sv[j] * inv);
        }
    } else if (bid < 2 * NN) {
        const int t = bid - NN;
        const int n0 = (t & 31) * 64;
        const int b = t >> 5;

#pragma unroll
        for (int l = 0; l < 4; ++l) {
            const int idx = tid + l * 256;
            const int nn = idx >> 4;
            const int c4 = (idx & 15) << 2;
            const float4 v = *(const float4*)(x + ((size_t)b * NN + n0 + nn) * CC + c4);
            tb[c4 + 0][nn] = v.x;
            tb[c4 + 1][nn] = v.y;
            tb[c4 + 2][nn] = v.z;
            tb[c4 + 3][nn] = v.w;
        }
        __syncthreads();

#pragma unroll
        for (int l = 0; l < 2; ++l) {
            const int idx = tid + l * 256;
            const int c = idx >> 3;
            const int ch = (idx & 7) << 3;
            ushort_t pack[8];
#pragma unroll
            for (int e = 0; e < 8; ++e) pack[e] = f2bf(tb[c][ch + e]);
            *(float4*)(xT + (size_t)(b * 64 + c) * NN + n0 + ch) = *(float4*)pack;
        }
#pragma unroll
        for (int l = 0; l < 2; ++l) {
            const int idx = tid + l * 256;
            const int nn = idx >> 3;
            const int cg = (idx & 7) << 3;
            ushort_t pack[8];
#pragma unroll
            for (int e = 0; e < 8; ++e) pack[e] = f2bf(tb[cg + e][nn]);
            *(float4*)(xN + (size_t)(n0 + nn) * JJ + b * 64 + cg) = *(float4*)pack;
        }
    } else {
        const int dk = bid - 2 * NN;
        const float* src = Wp + (size_t)dk * CC * CC;

#pragma unroll
        for (int l = 0; l < 4; ++l) {
            const int idx = tid + l * 256;
            const int i = idx >> 4;
            const int o4 = (idx & 15) << 2;
            const float4 v = *(const float4*)(src + i * CC + o4);
            tb[o4 + 0][i] = v.x;
            tb[o4 + 1][i] = v.y;
            tb[o4 + 2][i] = v.z;
            tb[o4 + 3][i] = v.w;
        }
        __syncthreads();

#pragma unroll
        for (int l = 0; l < 2; ++l) {
            const int idx = tid + l * 256;
            const int o = idx >> 3;
            const int ic = (idx & 7) << 3;
            ushort_t pack[8];
#pragma unroll
            for (int e = 0; e < 8; ++e) pack[e] = f2bf(tb[o][ic + e]);
            *(float4*)(WpT + (size_t)dk * CC * CC + o * CC + ic) = *(float4*)pack;
        }
    }
}

// ---------------------------------------------------------------------------
// Kernel 2: rolled NT-GEMM, 128x256 tile, 8 waves (2M x 4N, 64x64 per wave),
// BK=64, TRIPLE-buffered LDS (3 x 48 KB = 144 KB -> 1 block/CU, 8 waves).
// Grid 16x16 = 256 blocks = full machine per GEMM, M=2048 needs no fusion.
//
// Per tile (one region pair, 2 barriers): 2 MFMA clusters of 16 (same density
// as the 1090-TF gemm8; round-5's 8-MFMA clusters were the regression).
// Rolled: cluster C1 of tile t-1 is deferred to tile t's top, covering the
// vmcnt drain + the 12 top ds_reads. Stage lead = 2 tiles (3 buffers).
// vmcnt ledger: tile t top outstanding = {t?, t+1} -> vmcnt(6) ==> buf(t)
// landed (vmcnt(0) at t=31). Stage of t+2 overwrites buf(t-1), whose last
// reads are issue-ordered before it via tile t's top barrier.
//   MODE 0: y1T[j][m] (K-major) + y1N[m][j]   MODE 1: y2N = 2*acc - xN
// ---------------------------------------------------------------------------
#define STAGE_A(bp, kt) do {                                                                \
    __builtin_amdgcn_global_load_lds(                                                       \
        (gptr_t)(srcA + (size_t)(kt) * 64),                                                 \
        (lptr_t)&(bp)[dstoff], 16, 0, 0);                                                   \
    __builtin_amdgcn_global_load_lds(                                                       \
        (gptr_t)(srcA + (size_t)64 * NN + (size_t)(kt) * 64),                               \
        (lptr_t)&(bp)[4096 + dstoff], 16, 0, 0);                                            \
} while (0)

#define STAGE_B(bp, h, kt) do {                                                             \
    __builtin_amdgcn_global_load_lds(                                                       \
        (gptr_t)(srcB + (size_t)((h) * 2) * 64 * NN + (size_t)(kt) * 64),                   \
        (lptr_t)&(bp)[8192 + (h) * 8192 + dstoff], 16, 0, 0);                               \
    __builtin_amdgcn_global_load_lds(                                                       \
        (gptr_t)(srcB + (size_t)((h) * 2 + 1) * 64 * NN + (size_t)(kt) * 64),               \
        (lptr_t)&(bp)[8192 + (h) * 8192 + 4096 + dstoff], 16, 0, 0);                        \
} while (0)

#define LDA_ALL(bp) do {                                                                    \
    _Pragma("unroll") for (int mi_ = 0; mi_ < 4; ++mi_)                                     \
    _Pragma("unroll") for (int ks_ = 0; ks_ < 2; ++ks_)                                     \
        a[mi_][ks_] = *(ls8_t)&(bp)[(aRG + mi_) * 1024 + ks_ * 512 + rdofs];                \
} while (0)

#define LDB_H(bp, h) do {                                                                   \
    _Pragma("unroll") for (int nn_ = 0; nn_ < 2; ++nn_)                                     \
    _Pragma("unroll") for (int ks_ = 0; ks_ < 2; ++ks_)                                     \
        b[(h) * 2 + nn_][ks_] =                                                             \
            *(ls8_t)&(bp)[8192 + (bRG + (h) * 2 + nn_) * 1024 + ks_ * 512 + rdofs];         \
} while (0)

// cluster c covers ni = 2c..2c+1: 4 mi x 2 ni x 2 ks = 16 MFMAs
#define MFMA_C(c) do {                                                                      \
    __builtin_amdgcn_s_setprio(1);                                                          \
    _Pragma("unroll") for (int mi_ = 0; mi_ < 4; ++mi_)                                     \
    _Pragma("unroll") for (int nn_ = 0; nn_ < 2; ++nn_) {                                   \
        acc[mi_][(c) * 2 + nn_] = __builtin_amdgcn_mfma_f32_16x16x32_bf16(                  \
            a[mi_][0], b[(c) * 2 + nn_][0], acc[mi_][(c) * 2 + nn_], 0, 0, 0);              \
        acc[mi_][(c) * 2 + nn_] = __builtin_amdgcn_mfma_f32_16x16x32_bf16(                  \
            a[mi_][1], b[(c) * 2 + nn_][1], acc[mi_][(c) * 2 + nn_], 0, 0, 0);              \
    }                                                                                       \
    __builtin_amdgcn_s_setprio(0);                                                          \
} while (0)

template <int MODE>
__global__ __launch_bounds__(512, 2) void gemm_roll(const ushort_t* __restrict__ A,
                                                    const ushort_t* __restrict__ Bt,
                                                    const ushort_t* __restrict__ Zn,
                                                    ushort_t* __restrict__ Ct,
                                                    ushort_t* __restrict__ Cn) {
    // bijective XCD swizzle (256 % 8 == 0)
    int bid = blockIdx.x;
    bid = (bid & 7) * 32 + (bid >> 3);
    const int bx = bid & 15;        // j-tile (BN=256)
    const int by = bid >> 4;        // m-tile (BM=128)
    const int j0 = bx * 256;
    const int m0 = by * 128;

    const int tid = threadIdx.x;
    const int w = tid >> 6;
    const int lane = tid & 63;
    const int l16 = lane & 15;
    const int quad = lane >> 4;
    const int wm = (w >> 2) * 64;   // wave rows [wm, wm+64)
    const int wn = (w & 3) * 64;    // wave cols [wn, wn+64)
    const int aRG = (w >> 2) * 4;   // A subtile base (8 subtiles of 16 rows)
    const int bRG = (w & 3) * 4;    // B subtile base (16 subtiles)
    // swizzled ds_read offset (ushorts): row l16, k-chunk quad, st_16x32 XOR
    const int rdofs = l16 * 32 + ((quad * 8) ^ ((l16 & 8) * 2));

    // staging: linear LDS dest (tid*16B within 8KB unit); inverse-swz SOURCE
    const int r16s = lane >> 2;
    const int cx = (lane & 3) ^ ((r16s >> 3) << 1);
    const int rowbase = (w >> 1) * 16 + r16s;         // row within 64-row unit
    const int kofs = (w & 1) * 32 + cx * 8;
    const ushort_t* srcA = A + (size_t)(m0 + rowbase) * NN + kofs;
    const ushort_t* srcB = Bt + (size_t)(j0 + rowbase) * NN + kofs;
    const int dstoff = tid * 8;

    __shared__ ushort_t lds[3][24576];  // 3 x (A 16KB | B 32KB) = 144 KB

    lsptr_t p0 = (lsptr_t)&lds[0][0];   // buf(t)
    lsptr_t p1 = (lsptr_t)&lds[1][0];   // buf(t+1)
    lsptr_t p2 = (lsptr_t)&lds[2][0];   // buf(t+2) = stage target

    f32x4 acc[4][4];
#pragma unroll
    for (int mi = 0; mi < 4; ++mi)
#pragma unroll
        for (int ni = 0; ni < 4; ++ni) acc[mi][ni] = (f32x4){0.f, 0.f, 0.f, 0.f};

    short8 a[4][2], b[4][2];

    // Prologue: stage t0 (oldest) then t1. Loop-top vmcnt(6) drains t0.
    STAGE_A(p0, 0); STAGE_B(p0, 0, 0); STAGE_B(p0, 1, 0);
    STAGE_A(p1, 1); STAGE_B(p1, 0, 1); STAGE_B(p1, 1, 1);

#pragma unroll 1
    for (int t = 0; t < 32; ++t) {
        // deferred cluster of tile t-1 (old a, b[2..3]) covers drain + reads
        if (t) MFMA_C(1);
        if (t < 31) { asm volatile("s_waitcnt vmcnt(6)" ::: "memory"); }
        else        { asm volatile("s_waitcnt vmcnt(0)" ::: "memory"); }
        __builtin_amdgcn_sched_barrier(0);
        __builtin_amdgcn_s_barrier();          // buf(t) collectively landed

        LDA_ALL(p0); LDB_H(p0, 0);             // 12 ds_reads
        const bool stg = (t < 30);
        if (stg) { STAGE_A(p2, t + 2); STAGE_B(p2, 0, t + 2); }
        asm volatile("s_waitcnt lgkmcnt(0)" ::: "memory");
        __builtin_amdgcn_sched_barrier(0);
        MFMA_C(0);                              // 16 MFMAs cover:
        LDB_H(p0, 1);                           // 4 tail reads (b[2..3])
        if (stg) STAGE_B(p2, 1, t + 2);
        __builtin_amdgcn_sched_barrier(0);

        lsptr_t tp = p0; p0 = p1; p1 = p2; p2 = tp;  // rotate buffers
    }
    MFMA_C(1);  // tile 31's second cluster

    // Epilogue: C/D col j = l16, row m = quad*4 + r.
#pragma unroll
    for (int mi = 0; mi < 4; ++mi) {
#pragma unroll
        for (int ji = 0; ji < 4; ++ji) {
            const int j = j0 + wn + ji * 16 + l16;
            const int mb = m0 + wm + mi * 16 + quad * 4;
            if (MODE == 0) {
                ushort_t o[4];
#pragma unroll
                for (int r = 0; r < 4; ++r) o[r] = f2bf(acc[mi][ji][r]);
                *(unsigned long long*)(Ct + (size_t)j * NN + mb) = *(unsigned long long*)o;
#pragma unroll
                for (int r = 0; r < 4; ++r) Cn[(size_t)(mb + r) * JJ + j] = o[r];
            } else {
#pragma unroll
                for (int r = 0; r < 4; ++r) {
                    const float z = bf2f(Zn[(size_t)(mb + r) * JJ + j]);
                    Cn[(size_t)(mb + r) * JJ + j] = f2bf(2.0f * acc[mi][ji][r] - z);
                }
            }
        }
    }
}

#undef STAGE_A
#undef STAGE_B
#undef LDA_ALL
#undef LDB_H
#undef MFMA_C

// ---------------------------------------------------------------------------
// Kernel 3: MFMA epilogue (identical to the verified round-0 version).
// ---------------------------------------------------------------------------
#define XLD 200  // LDS row stride (bf16): 400 B -> 2-way bank alias (free)
__global__ __launch_bounds__(256) void out_kernel(const float* __restrict__ E,
                                                  const ushort_t* __restrict__ WpT,
                                                  const float* __restrict__ bp,
                                                  const ushort_t* __restrict__ xN,
                                                  const ushort_t* __restrict__ y1N,
                                                  const ushort_t* __restrict__ y2N,
                                                  float* __restrict__ out) {
    const int n = blockIdx.x;
    const int tid = threadIdx.x;

    __shared__ ushort_t xg[BB * XLD];
    __shared__ ushort_t Wt[CC * XLD];
    __shared__ float en_s[ED];
    __shared__ float bias_s[CC];

    if (tid < ED) en_s[tid] = E[n * ED + tid];
    __syncthreads();

    float en[ED];
#pragma unroll
    for (int d = 0; d < ED; ++d) en[d] = en_s[d];

    if (tid < CC) {
        float bsum = 0.0f;
#pragma unroll
        for (int d = 0; d < ED; ++d) bsum += en[d] * bp[d * CC + tid];
        bias_s[tid] = bsum;
    }

#pragma unroll
    for (int k = 0; k < KK; ++k) {
        const ushort_t* src = (k == 0) ? xN : (k == 1) ? y1N : y2N;
        const float4* srow = (const float4*)(src + (size_t)n * JJ);
        for (int idx = tid; idx < JJ / 8; idx += 256) {
            *(float4*)&xg[(idx >> 3) * XLD + k * 64 + ((idx & 7) << 3)] = srow[idx];
        }
    }

    for (int t = tid; t < CC * 24; t += 256) {
        const int o = t / 24;
        const int kc = t % 24;
        const int k = kc >> 3;
        const int ic = (kc & 7) << 3;
        float s[8];
#pragma unroll
        for (int e = 0; e < 8; ++e) s[e] = 0.0f;
#pragma unroll
        for (int d = 0; d < ED; ++d) {
            const float4 wv4 = *(const float4*)(WpT + ((size_t)(d * KK + k) * CC + o) * CC + ic);
            const ushort_t* wp = (const ushort_t*)&wv4;
#pragma unroll
            for (int e = 0; e < 8; ++e) s[e] += en[d] * bf2f(wp[e]);
        }
        ushort_t pack[8];
#pragma unroll
        for (int e = 0; e < 8; ++e) pack[e] = f2bf(s[e]);
        *(float4*)&Wt[o * XLD + k * 64 + ic] = *(float4*)pack;
    }
    __syncthreads();

    const int lane = tid & 63;
    const int l16 = lane & 15;
    const int quad = lane >> 4;
    const int bm = (tid >> 6) * 16;

    f32x4 acc[4];
#pragma unroll
    for (int ji = 0; ji < 4; ++ji) acc[ji] = (f32x4){0.f, 0.f, 0.f, 0.f};

#pragma unroll
    for (int kc = 0; kc < 6; ++kc) {
        const short8 av = *(const short8*)&xg[(bm + l16) * XLD + kc * 32 + quad * 8];
#pragma unroll
        for (int ji = 0; ji < 4; ++ji) {
            const short8 bv = *(const short8*)&Wt[(ji * 16 + l16) * XLD + kc * 32 + quad * 8];
            acc[ji] = __builtin_amdgcn_mfma_f32_16x16x32_bf16(av, bv, acc[ji], 0, 0, 0);
        }
    }

#pragma unroll
    for (int ji = 0; ji < 4; ++ji) {
        const int o = ji * 16 + l16;
        const float bo = bias_s[o];
#pragma unroll
        for (int r = 0; r < 4; ++r) {
            const int b = bm + quad * 4 + r;
            out[((size_t)b * NN + n) * CC + o] = acc[ji][r] + bo;
        }
    }
}
#undef XLD

// ---------------------------------------------------------------------------
// Host launch: 4 dispatches (round-0 structure, rolled GEMMs).
// Workspace (bf16): Ab 8 | xT 16 | xN 16 | y1T 16 | y1N 16 | y2N 16
//   | WpT 0.24  = 88.25 MB.
// ---------------------------------------------------------------------------
extern "C" void kernel_launch(void* const* d_in, const int* in_sizes, int n_in,
                              void* d_out, int out_size, void* d_ws, size_t ws_size,
                              hipStream_t stream) {
    const float* x  = (const float*)d_in[0];
    const float* E  = (const float*)d_in[1];
    const float* Wp = (const float*)d_in[2];
    const float* bp = (const float*)d_in[3];

    ushort_t* Ab  = (ushort_t*)d_ws;                    // [2048][2048]
    ushort_t* xT  = Ab + (size_t)NN * NN;               // [4096][2048]
    ushort_t* xN  = xT + (size_t)JJ * NN;               // [2048][4096]
    ushort_t* y1T = xN + (size_t)NN * JJ;               // [4096][2048]
    ushort_t* y1N = y1T + (size_t)JJ * NN;              // [2048][4096]
    ushort_t* y2N = y1N + (size_t)NN * JJ;              // [2048][4096]
    ushort_t* WpT = y2N + (size_t)NN * JJ;              // [30][64][64]
    float* out = (float*)d_out;

    prep_kernel<<<2 * NN + ED * KK, 256, 0, stream>>>(E, x, Wp, Ab, xT, xN, WpT);
    // y1 = A @ x : dual output (K-major + node-major)
    gemm_roll<0><<<256, 512, 0, stream>>>(Ab, xT, nullptr, y1T, y1N);
    // y2 = 2 A @ y1 - x : node-major only
    gemm_roll<1><<<256, 512, 0, stream>>>(Ab, y1T, xN, nullptr, y2N);
    out_kernel<<<NN, 256, 0, stream>>>(E, WpT, bp, xN, y1N, y2N, out);
}